// Round 2
// baseline (10210.519 us; speedup 1.0000x reference)
//
#include <hip/hip_runtime.h>

#define T_STEPS 1024
#define BATCH   64
#define NDIM    256
#define HID     256
#define G4      1024   // 4*H

typedef short bf16x8 __attribute__((ext_vector_type(8)));
typedef float f32x4  __attribute__((ext_vector_type(4)));
typedef unsigned short u16;

__device__ __forceinline__ float b2f(u16 v) {
  union { unsigned u; float f; } c; c.u = ((unsigned)v) << 16; return c.f;
}
__device__ __forceinline__ u16 f2b(float f) {
  union { float f; unsigned u; } c; c.f = f;
  unsigned u = c.u;
  u += 0x7fffu + ((u >> 16) & 1u);   // round-to-nearest-even
  return (u16)(u >> 16);
}
__device__ __forceinline__ float sigm(float x) {
  float e = __expf(-x);
  return __builtin_amdgcn_rcpf(1.0f + e);
}
__device__ __forceinline__ float tanh_f(float x) {
  return 2.0f * sigm(2.0f * x) - 1.0f;
}

// ---------------------------------------------------------------------------
// Phase 1: xw[d][t][b][col] = (x[t] @ W_d)[b][col] + bias_d[col], bf16 in ws.
// Inputs are FLOAT32 (per reference). Convert to bf16 during LDS staging /
// W-fragment load. grid (16,16): bx -> t-chunk of 64; by: d = y>>3, ntile=y&7.
// 256 threads (4 waves); W-frags persistent in VGPRs, amortized over 64 t.
// ---------------------------------------------------------------------------
__global__ __launch_bounds__(256) void xw_gemm(
    const float* __restrict__ x,
    const float* __restrict__ W0, const float* __restrict__ W1,
    const float* __restrict__ b0, const float* __restrict__ b1,
    u16* __restrict__ xw)
{
  const int d  = blockIdx.y >> 3;
  const int n0 = (blockIdx.y & 7) * 128;
  const int t0 = blockIdx.x * 64;
  const float* __restrict__ W    = d ? W1 : W0;
  const float* __restrict__ bias = d ? b1 : b0;
  const int lane = threadIdx.x & 63;
  const int wv   = threadIdx.x >> 6;
  const int q    = lane >> 4;
  const int c15  = lane & 15;

  // B-operand fragments: B[k = kf*32 + q*8 + j][n = col], col = n0 + ct*16 + c15
  bf16x8 uf[8][8];
  #pragma unroll
  for (int ct = 0; ct < 8; ++ct) {
    const int col = n0 + ct * 16 + c15;
    #pragma unroll
    for (int kf = 0; kf < 8; ++kf) {
      #pragma unroll
      for (int j = 0; j < 8; ++j)
        uf[ct][kf][j] = (short)f2b(W[(size_t)(kf * 32 + q * 8 + j) * G4 + col]);
    }
  }
  float bc[8];
  #pragma unroll
  for (int ct = 0; ct < 8; ++ct) bc[ct] = bias[n0 + ct * 16 + c15];

  // x[t] tile: 64 rows x 256 cols bf16, XOR-swizzled 16B chunks (<=2-way = free)
  __shared__ __align__(16) u16 Alds[64 * 256];

  for (int t = t0; t < t0 + 64; ++t) {
    __syncthreads();   // previous iteration's reads done
    const float* xt = x + (size_t)t * BATCH * NDIM;
    #pragma unroll
    for (int i = 0; i < 8; ++i) {
      int g = (int)threadIdx.x + 256 * i;   // bf16 16B chunk id 0..2047
      int r = g >> 5, c = g & 31;
      const float* src = xt + r * 256 + c * 8;  // 8 consecutive f32, coalesced
      bf16x8 v;
      #pragma unroll
      for (int j = 0; j < 8; ++j) v[j] = (short)f2b(src[j]);
      int cs = (c & 16) | ((c ^ (r & 15)) & 15);
      ((bf16x8*)Alds)[r * 32 + cs] = v;
    }
    __syncthreads();

    bf16x8 af[8];
    const int arow = wv * 16 + c15;          // A[m = lane&15 within tile]
    #pragma unroll
    for (int kf = 0; kf < 8; ++kf) {
      int c = kf * 4 + q;
      int cs = (c & 16) | ((c ^ c15) & 15);  // arow & 15 == c15
      af[kf] = ((const bf16x8*)Alds)[arow * 32 + cs];
    }

    f32x4 acc[8];
    #pragma unroll
    for (int ct = 0; ct < 8; ++ct) acc[ct] = (f32x4){0.f, 0.f, 0.f, 0.f};
    #pragma unroll
    for (int kf = 0; kf < 8; ++kf) {
      #pragma unroll
      for (int ct = 0; ct < 8; ++ct)
        acc[ct] = __builtin_amdgcn_mfma_f32_16x16x32_bf16(af[kf], uf[ct][kf], acc[ct], 0, 0, 0);
    }

    u16* dst = xw + ((size_t)d * T_STEPS + t) * BATCH * G4;
    #pragma unroll
    for (int ct = 0; ct < 8; ++ct) {
      #pragma unroll
      for (int r = 0; r < 4; ++r) {
        int brow = wv * 16 + q * 4 + r;      // C/D: row = quad*4 + reg
        dst[(size_t)brow * G4 + n0 + ct * 16 + c15] = f2b(acc[ct][r] + bc[ct]);
      }
    }
  }
}

// ---------------------------------------------------------------------------
// Phase 2: sequential scan. grid = 8 wgs: d = bx>>2, batch-tile (16) = bx&3.
// 1024 threads (16 waves); wave w owns z-cols {g*256 + w*16 + c}. U-frags
// (128 VGPRs) persistent in registers; h ping-pongs through swizzled LDS;
// c-state in registers. xw prefetched one full step ahead (raw u16, convert
// at use) so HBM/L3 latency hides behind a whole step's MFMA+gates.
// ---------------------------------------------------------------------------
#define LSTM_STEP(IT, XVC, XVN)                                                  \
  do {                                                                           \
    const int it = (IT);                                                         \
    const int t  = d ? (T_STEPS - 1 - it) : it;                                  \
    const int itn = (it + 1 < T_STEPS) ? (it + 1) : it;                          \
    const int tn  = d ? (T_STEPS - 1 - itn) : itn;                               \
    const u16* xwn = xw + (((size_t)d * T_STEPS + tn) * BATCH + rowbase) * G4;   \
    _Pragma("unroll") for (int g = 0; g < 4; ++g)                                \
      _Pragma("unroll") for (int r = 0; r < 4; ++r)                              \
        XVN[g][r] = xwn[(size_t)(q * 4 + r) * G4 + g * 256 + col];               \
    const int cur = it & 1;                                                      \
    bf16x8 af[8];                                                                \
    _Pragma("unroll") for (int kf = 0; kf < 8; ++kf) {                           \
      int cc = kf * 4 + q;                                                       \
      int cs = (cc & 16) | ((cc ^ c15) & 15);                                    \
      af[kf] = ((const bf16x8*)hbuf[cur])[c15 * 32 + cs];                        \
    }                                                                            \
    f32x4 acc[4];                                                                \
    _Pragma("unroll") for (int g = 0; g < 4; ++g)                                \
      acc[g] = (f32x4){0.f, 0.f, 0.f, 0.f};                                      \
    _Pragma("unroll") for (int kf = 0; kf < 8; ++kf)                             \
      _Pragma("unroll") for (int g = 0; g < 4; ++g)                              \
        acc[g] = __builtin_amdgcn_mfma_f32_16x16x32_bf16(af[kf], uf[g][kf],      \
                                                         acc[g], 0, 0, 0);      \
    u16 hb[4]; float hv[4];                                                      \
    _Pragma("unroll") for (int r = 0; r < 4; ++r) {                              \
      float zf = acc[0][r] + b2f(XVC[0][r]);                                     \
      float zg = acc[1][r] + b2f(XVC[1][r]);                                     \
      float zi = acc[2][r] + b2f(XVC[2][r]);                                     \
      float zo = acc[3][r] + b2f(XVC[3][r]);                                     \
      float fg = sigm(zf);                                                       \
      float gg = tanh_f(zg);                                                     \
      float ig = sigm(zi);                                                       \
      float og = sigm(zo);                                                       \
      float cn = cst[r] * fg + gg * ig;                                          \
      cst[r] = cn;                                                               \
      hv[r] = og * tanh_f(cn);                                                   \
      hb[r] = f2b(hv[r]);                                                        \
    }                                                                            \
    const int nxt = cur ^ 1;                                                     \
    _Pragma("unroll") for (int r = 0; r < 4; ++r) {                              \
      const int row = q * 4 + r;                                                 \
      int cch = col >> 3;                                                        \
      int cs = (cch & 16) | ((cch ^ row) & 15);                                  \
      hbuf[nxt][(row * 32 + cs) * 8 + (col & 7)] = hb[r];                        \
      out[((size_t)t * BATCH + rowbase + row) * (2 * HID) + (size_t)d * HID +    \
          col] = hv[r];                                                          \
    }                                                                            \
    if (it == T_STEPS - 1) {                                                     \
      _Pragma("unroll") for (int r = 0; r < 4; ++r) {                            \
        const int row = q * 4 + r;                                               \
        out[hlast_base + (size_t)(rowbase + row) * HID + col] = hv[r];           \
      }                                                                          \
    }                                                                            \
    __syncthreads();                                                             \
  } while (0)

__global__ __launch_bounds__(1024) void lstm_scan(
    const u16* __restrict__ xw,
    const float* __restrict__ U0, const float* __restrict__ U1,
    float* __restrict__ out)
{
  const int d  = blockIdx.x >> 2;
  const int bt = blockIdx.x & 3;
  const int w    = threadIdx.x >> 6;
  const int lane = threadIdx.x & 63;
  const int q    = lane >> 4;
  const int c15  = lane & 15;
  const float* __restrict__ U = d ? U1 : U0;

  // B-fragments of U: uf[g][kf], B[k = kf*32 + q*8 + j][n = g*256 + w*16 + c15]
  bf16x8 uf[4][8];
  #pragma unroll
  for (int g = 0; g < 4; ++g) {
    const int col = g * 256 + w * 16 + c15;
    #pragma unroll
    for (int kf = 0; kf < 8; ++kf) {
      #pragma unroll
      for (int j = 0; j < 8; ++j)
        uf[g][kf][j] = (short)f2b(U[(size_t)(kf * 32 + q * 8 + j) * G4 + col]);
    }
  }

  __shared__ __align__(16) u16 hbuf[2][16 * 256];   // [buf][row 16][col 256] swizzled
  for (int i = threadIdx.x; i < 16 * 256; i += 1024) {
    hbuf[0][i] = 0; hbuf[1][i] = 0;
  }
  float cst[4] = {0.f, 0.f, 0.f, 0.f};   // c state (row = q*4+r, col = w*16+c15)
  __syncthreads();

  const int rowbase = bt * 16;
  const int col = w * 16 + c15;
  const size_t hlast_base = (size_t)T_STEPS * BATCH * (2 * HID) + (size_t)d * BATCH * HID;

  // prefetch step 0's xw (raw u16; converted at use)
  u16 xvA[4][4], xvB[4][4];
  {
    const int t0 = d ? (T_STEPS - 1) : 0;
    const u16* xw0 = xw + (((size_t)d * T_STEPS + t0) * BATCH + rowbase) * G4;
    #pragma unroll
    for (int g = 0; g < 4; ++g)
      #pragma unroll
      for (int r = 0; r < 4; ++r)
        xvA[g][r] = xw0[(size_t)(q * 4 + r) * G4 + g * 256 + col];
  }

  for (int it2 = 0; it2 < T_STEPS; it2 += 2) {
    LSTM_STEP(it2,     xvA, xvB);
    LSTM_STEP(it2 + 1, xvB, xvA);
  }
}

extern "C" void kernel_launch(void* const* d_in, const int* in_sizes, int n_in,
                              void* d_out, int out_size, void* d_ws, size_t ws_size,
                              hipStream_t stream) {
  const float* x  = (const float*)d_in[0];
  const float* fW = (const float*)d_in[1];
  const float* fU = (const float*)d_in[2];
  const float* fb = (const float*)d_in[3];
  const float* bW = (const float*)d_in[4];
  const float* bU = (const float*)d_in[5];
  const float* bb = (const float*)d_in[6];
  u16*   xwbuf = (u16*)d_ws;        // 2 * T * B * 4H bf16 = 256 MiB scratch
  float* out   = (float*)d_out;

  dim3 g1(16, 16);
  xw_gemm<<<g1, 256, 0, stream>>>(x, fW, bW, fb, bb, xwbuf);
  lstm_scan<<<8, 1024, 0, stream>>>(xwbuf, fU, bU, out);
}

// Round 3
// 5007.265 us; speedup vs baseline: 2.0391x; 2.0391x over previous
//
#include <hip/hip_runtime.h>

#define T_STEPS 1024
#define BATCH   64
#define NDIM    256
#define HID     256
#define G4      1024   // 4*H

typedef short bf16x8 __attribute__((ext_vector_type(8)));
typedef float f32x4  __attribute__((ext_vector_type(4)));
typedef unsigned short u16;

#define XW_ELEMS ((size_t)2 * T_STEPS * BATCH * G4)   // 134217728 u16 (256 MiB)
#define UT_ELEMS ((size_t)2 * 4 * 65536)              // 524288 u16 (1 MiB)

__device__ __forceinline__ float b2f(u16 v) {
  union { unsigned u; float f; } c; c.u = ((unsigned)v) << 16; return c.f;
}
__device__ __forceinline__ u16 f2b(float f) {
  union { float f; unsigned u; } c; c.f = f;
  unsigned u = c.u;
  u += 0x7fffu + ((u >> 16) & 1u);   // round-to-nearest-even
  return (u16)(u >> 16);
}
__device__ __forceinline__ float sigm(float x) {
  float e = __expf(-x);
  return __builtin_amdgcn_rcpf(1.0f + e);
}
__device__ __forceinline__ float tanh_f(float x) {
  return 2.0f * sigm(2.0f * x) - 1.0f;
}

// ---------------------------------------------------------------------------
// build_ut: pre-transpose U (f32) into bf16 MFMA B-fragment order.
// UT elem idx: ((d*4+g)*65536) + ((w*8+kf)*64 + lane)*8 + j
//   value = U_d[(kf*32 + (lane>>4)*8 + j)*G4 + g*256 + w*16 + (lane&15)]
// grid 8: d = bx>>2, g = bx&3; 1024 threads.
// ---------------------------------------------------------------------------
__global__ __launch_bounds__(1024) void build_ut(
    const float* __restrict__ U0, const float* __restrict__ U1,
    u16* __restrict__ UT)
{
  const int d = blockIdx.x >> 2;
  const int g = blockIdx.x & 3;
  const float* __restrict__ U = d ? U1 : U0;
  const int w = threadIdx.x >> 6, lane = threadIdx.x & 63;
  const int q = lane >> 4, c15 = lane & 15;
  u16* dst = UT + ((size_t)d * 4 + g) * 65536;
  #pragma unroll
  for (int kf = 0; kf < 8; ++kf) {
    bf16x8 v;
    #pragma unroll
    for (int j = 0; j < 8; ++j)
      v[j] = (short)f2b(U[(size_t)(kf * 32 + q * 8 + j) * G4 + g * 256 + w * 16 + c15]);
    ((bf16x8*)dst)[((w * 8 + kf) << 6) + lane] = v;
  }
}

// ---------------------------------------------------------------------------
// Phase 1: xw = x @ W_d + b_d, bf16, stored in SCAN-CONSUMPTION order:
//   elem idx = (((d*T + t)*4 + bt)*1024 + tid)*16 + gate*4 + r
// so each scan thread reads its 16 pre-activations as 2 x dwordx4.
// ---------------------------------------------------------------------------
__global__ __launch_bounds__(256) void xw_gemm(
    const float* __restrict__ x,
    const float* __restrict__ W0, const float* __restrict__ W1,
    const float* __restrict__ b0, const float* __restrict__ b1,
    u16* __restrict__ xw)
{
  const int d  = blockIdx.y >> 3;
  const int n0 = (blockIdx.y & 7) * 128;
  const int t0 = blockIdx.x * 64;
  const float* __restrict__ W    = d ? W1 : W0;
  const float* __restrict__ bias = d ? b1 : b0;
  const int lane = threadIdx.x & 63;
  const int wv   = threadIdx.x >> 6;
  const int q    = lane >> 4;
  const int c15  = lane & 15;

  // B-operand fragments: B[k = kf*32 + q*8 + j][n = col], col = n0 + ct*16 + c15
  bf16x8 uf[8][8];
  #pragma unroll
  for (int ct = 0; ct < 8; ++ct) {
    const int col = n0 + ct * 16 + c15;
    #pragma unroll
    for (int kf = 0; kf < 8; ++kf) {
      #pragma unroll
      for (int j = 0; j < 8; ++j)
        uf[ct][kf][j] = (short)f2b(W[(size_t)(kf * 32 + q * 8 + j) * G4 + col]);
    }
  }
  float bc[8];
  #pragma unroll
  for (int ct = 0; ct < 8; ++ct) bc[ct] = bias[n0 + ct * 16 + c15];

  __shared__ __align__(16) u16 Alds[64 * 256];

  for (int t = t0; t < t0 + 64; ++t) {
    __syncthreads();
    const float* xt = x + (size_t)t * BATCH * NDIM;
    #pragma unroll
    for (int i = 0; i < 8; ++i) {
      int g = (int)threadIdx.x + 256 * i;
      int r = g >> 5, c = g & 31;
      const float* src = xt + r * 256 + c * 8;
      bf16x8 v;
      #pragma unroll
      for (int j = 0; j < 8; ++j) v[j] = (short)f2b(src[j]);
      int cs = (c & 16) | ((c ^ (r & 15)) & 15);
      ((bf16x8*)Alds)[r * 32 + cs] = v;
    }
    __syncthreads();

    bf16x8 af[8];
    const int arow = wv * 16 + c15;
    #pragma unroll
    for (int kf = 0; kf < 8; ++kf) {
      int c = kf * 4 + q;
      int cs = (c & 16) | ((c ^ c15) & 15);
      af[kf] = ((const bf16x8*)Alds)[arow * 32 + cs];
    }

    f32x4 acc[8];
    #pragma unroll
    for (int ct = 0; ct < 8; ++ct) acc[ct] = (f32x4){0.f, 0.f, 0.f, 0.f};
    #pragma unroll
    for (int kf = 0; kf < 8; ++kf) {
      #pragma unroll
      for (int ct = 0; ct < 8; ++ct)
        acc[ct] = __builtin_amdgcn_mfma_f32_16x16x32_bf16(af[kf], uf[ct][kf], acc[ct], 0, 0, 0);
    }

    // store in scan order; bt == wv (row tile)
    u16* dst = xw + (((size_t)d * T_STEPS + t) * 4 + wv) * 16384;
    #pragma unroll
    for (int ct = 0; ct < 8; ++ct) {
      int ncol = n0 + ct * 16;
      int g2 = ncol >> 8, w2 = (ncol >> 4) & 15;
      #pragma unroll
      for (int r = 0; r < 4; ++r)
        dst[(size_t)(w2 * 64 + q * 16 + c15) * 16 + g2 * 4 + r] = f2b(acc[ct][r] + bc[ct]);
    }
  }
}

// ---------------------------------------------------------------------------
// Phase 2 (fast): grid 8 = (d, bt). 1024 threads, 16 waves; wave w owns
// h-cols [w*16, w*16+16). U split by gate to fit the CU:
//   gates f,g: 64 VGPRs persistent; gate i: 128 KB LDS; gate o: streamed
//   from L2 each step (rolling prefetch). h ping-pongs through 16 KB LDS.
// Dynamic LDS 147456 B: [0,8192) u16 hbuf ping-pong, [8192,73728) U_i frags.
// ---------------------------------------------------------------------------
__global__ __launch_bounds__(1024) void lstm_scan_fast(
    const u16* __restrict__ xw, const u16* __restrict__ UT,
    float* __restrict__ out)
{
  extern __shared__ __align__(16) u16 dynlds[];
  const int d  = blockIdx.x >> 2;
  const int bt = blockIdx.x & 3;
  const int tid  = threadIdx.x;
  const int w    = tid >> 6;
  const int lane = tid & 63;
  const int q    = lane >> 4;
  const int c15  = lane & 15;

  const u16* __restrict__ UTd = UT + (size_t)d * 4 * 65536;

  // persistent register fragments for gates f(0), g(1)
  bf16x8 uf0[8], uf1[8];
  const bf16x8* UTf = (const bf16x8*)UTd;
  #pragma unroll
  for (int kf = 0; kf < 8; ++kf) {
    uf0[kf] = UTf[0 * 8192 + ((w * 8 + kf) << 6) + lane];
    uf1[kf] = UTf[1 * 8192 + ((w * 8 + kf) << 6) + lane];
  }

  // stage i-gate (g=2) into LDS (coalesced 128 KB copy) + zero hbuf
  {
    const int4* src = (const int4*)(UTd + 2 * 65536);
    int4* dstl = (int4*)(dynlds + 8192);
    for (int i = tid; i < 8192; i += 1024) dstl[i] = src[i];
    for (int i = tid; i < 8192; i += 1024) dynlds[i] = 0;
  }

  const int4* __restrict__ Uo4 = (const int4*)(UTd + 3 * 65536);
  const bf16x8* uldsf = (const bf16x8*)(dynlds + 8192);

  float cst[4] = {0.f, 0.f, 0.f, 0.f};
  __syncthreads();

  const int rowbase = bt * 16;
  const int col = w * 16 + c15;
  const int obase = (w << 9) | lane;   // (w*8 + kf)*64 + lane at kf=0
  const size_t hlast_base = (size_t)T_STEPS * BATCH * (2 * HID) + (size_t)d * BATCH * HID;

  for (int it = 0; it < T_STEPS; ++it) {
    const int t = d ? (T_STEPS - 1 - it) : it;

    // xw pre-activations: 16 contiguous u16 per thread (2 x dwordx4)
    union { int4 v[2]; u16 s[16]; } xv;
    {
      const int4* xwt = (const int4*)(xw + ((((size_t)d * T_STEPS + t) * 4 + bt) * 1024 + tid) * 16);
      xv.v[0] = xwt[0]; xv.v[1] = xwt[1];
    }

    const int cur = it & 1;
    const bf16x8* hcur = (const bf16x8*)dynlds + cur * 512;

    int4 ofr[3];                       // rolling o-gate L2 prefetch
    ofr[0] = Uo4[obase];
    ofr[1] = Uo4[obase + 64];

    f32x4 acc0 = {0,0,0,0}, acc1 = {0,0,0,0}, acc2 = {0,0,0,0}, acc3 = {0,0,0,0};
    bf16x8 afb[2], uib[2];
    {
      int cs = (q & 16) | ((q ^ c15) & 15);   // kf = 0: cc = q
      afb[0] = hcur[c15 * 32 + cs];
      uib[0] = uldsf[obase];
    }
    #pragma unroll
    for (int kf = 0; kf < 8; ++kf) {
      if (kf < 7) {
        int cc = (kf + 1) * 4 + q;
        int cs = (cc & 16) | ((cc ^ c15) & 15);
        afb[(kf + 1) & 1] = hcur[c15 * 32 + cs];
        uib[(kf + 1) & 1] = uldsf[obase + ((kf + 1) << 6)];
      }
      if (kf < 6) ofr[(kf + 2) % 3] = Uo4[obase + ((kf + 2) << 6)];
      bf16x8 af = afb[kf & 1];
      union { int4 v; bf16x8 b; } oc; oc.v = ofr[kf % 3];
      acc0 = __builtin_amdgcn_mfma_f32_16x16x32_bf16(af, uf0[kf],     acc0, 0, 0, 0);
      acc1 = __builtin_amdgcn_mfma_f32_16x16x32_bf16(af, uf1[kf],     acc1, 0, 0, 0);
      acc2 = __builtin_amdgcn_mfma_f32_16x16x32_bf16(af, uib[kf & 1], acc2, 0, 0, 0);
      acc3 = __builtin_amdgcn_mfma_f32_16x16x32_bf16(af, oc.b,        acc3, 0, 0, 0);
    }

    u16 hb[4]; float hv[4];
    #pragma unroll
    for (int r = 0; r < 4; ++r) {
      float zf = acc0[r] + b2f(xv.s[0 * 4 + r]);
      float zg = acc1[r] + b2f(xv.s[1 * 4 + r]);
      float zi = acc2[r] + b2f(xv.s[2 * 4 + r]);
      float zo = acc3[r] + b2f(xv.s[3 * 4 + r]);
      float fg = sigm(zf);
      float gg = tanh_f(zg);
      float ig = sigm(zi);
      float og = sigm(zo);
      float cn = cst[r] * fg + gg * ig;
      cst[r] = cn;
      hv[r] = og * tanh_f(cn);
      hb[r] = f2b(hv[r]);
    }

    const int nxt = cur ^ 1;
    #pragma unroll
    for (int r = 0; r < 4; ++r) {
      const int row = q * 4 + r;
      int cch = col >> 3;
      int cs = (cch & 16) | ((cch ^ row) & 15);
      dynlds[nxt * 4096 + (row * 32 + cs) * 8 + (col & 7)] = hb[r];
      out[((size_t)t * BATCH + rowbase + row) * (2 * HID) + (size_t)d * HID + col] = hv[r];
    }
    if (it == T_STEPS - 1) {
      #pragma unroll
      for (int r = 0; r < 4; ++r)
        out[hlast_base + (size_t)(rowbase + q * 4 + r) * HID + col] = hv[r];
    }
    __syncthreads();
  }
}

// ---------------------------------------------------------------------------
// Phase 2 (safe fallback, ws too small for UT): round-2 structure (spills,
// slow, but correct). Reads new xw layout.
// ---------------------------------------------------------------------------
__global__ __launch_bounds__(1024) void lstm_scan_safe(
    const u16* __restrict__ xw,
    const float* __restrict__ U0, const float* __restrict__ U1,
    float* __restrict__ out)
{
  const int d  = blockIdx.x >> 2;
  const int bt = blockIdx.x & 3;
  const int tid  = threadIdx.x;
  const int w    = tid >> 6;
  const int lane = tid & 63;
  const int q    = lane >> 4;
  const int c15  = lane & 15;
  const float* __restrict__ U = d ? U1 : U0;

  bf16x8 uf[4][8];
  #pragma unroll
  for (int g = 0; g < 4; ++g) {
    const int col2 = g * 256 + w * 16 + c15;
    #pragma unroll
    for (int kf = 0; kf < 8; ++kf) {
      #pragma unroll
      for (int j = 0; j < 8; ++j)
        uf[g][kf][j] = (short)f2b(U[(size_t)(kf * 32 + q * 8 + j) * G4 + col2]);
    }
  }

  __shared__ __align__(16) u16 hbuf[2][16 * 256];
  for (int i = tid; i < 16 * 256; i += 1024) { hbuf[0][i] = 0; hbuf[1][i] = 0; }
  float cst[4] = {0.f, 0.f, 0.f, 0.f};
  __syncthreads();

  const int rowbase = bt * 16;
  const int col = w * 16 + c15;
  const size_t hlast_base = (size_t)T_STEPS * BATCH * (2 * HID) + (size_t)d * BATCH * HID;

  for (int it = 0; it < T_STEPS; ++it) {
    const int t = d ? (T_STEPS - 1 - it) : it;
    union { int4 v[2]; u16 s[16]; } xv;
    {
      const int4* xwt = (const int4*)(xw + ((((size_t)d * T_STEPS + t) * 4 + bt) * 1024 + tid) * 16);
      xv.v[0] = xwt[0]; xv.v[1] = xwt[1];
    }
    const int cur = it & 1;
    bf16x8 af[8];
    #pragma unroll
    for (int kf = 0; kf < 8; ++kf) {
      int cc = kf * 4 + q;
      int cs = (cc & 16) | ((cc ^ c15) & 15);
      af[kf] = ((const bf16x8*)hbuf[cur])[c15 * 32 + cs];
    }
    f32x4 acc[4];
    #pragma unroll
    for (int g = 0; g < 4; ++g) acc[g] = (f32x4){0.f, 0.f, 0.f, 0.f};
    #pragma unroll
    for (int kf = 0; kf < 8; ++kf)
      #pragma unroll
      for (int g = 0; g < 4; ++g)
        acc[g] = __builtin_amdgcn_mfma_f32_16x16x32_bf16(af[kf], uf[g][kf], acc[g], 0, 0, 0);

    u16 hb[4]; float hv[4];
    #pragma unroll
    for (int r = 0; r < 4; ++r) {
      float zf = acc[0][r] + b2f(xv.s[0 * 4 + r]);
      float zg = acc[1][r] + b2f(xv.s[1 * 4 + r]);
      float zi = acc[2][r] + b2f(xv.s[2 * 4 + r]);
      float zo = acc[3][r] + b2f(xv.s[3 * 4 + r]);
      float fg = sigm(zf), gg = tanh_f(zg), ig = sigm(zi), og = sigm(zo);
      float cn = cst[r] * fg + gg * ig;
      cst[r] = cn;
      hv[r] = og * tanh_f(cn);
      hb[r] = f2b(hv[r]);
    }
    const int nxt = cur ^ 1;
    #pragma unroll
    for (int r = 0; r < 4; ++r) {
      const int row = q * 4 + r;
      int cch = col >> 3;
      int cs = (cch & 16) | ((cch ^ row) & 15);
      hbuf[nxt][(row * 32 + cs) * 8 + (col & 7)] = hb[r];
      out[((size_t)t * BATCH + rowbase + row) * (2 * HID) + (size_t)d * HID + col] = hv[r];
    }
    if (it == T_STEPS - 1) {
      #pragma unroll
      for (int r = 0; r < 4; ++r)
        out[hlast_base + (size_t)(rowbase + q * 4 + r) * HID + col] = hv[r];
    }
    __syncthreads();
  }
}

extern "C" void kernel_launch(void* const* d_in, const int* in_sizes, int n_in,
                              void* d_out, int out_size, void* d_ws, size_t ws_size,
                              hipStream_t stream) {
  const float* x  = (const float*)d_in[0];
  const float* fW = (const float*)d_in[1];
  const float* fU = (const float*)d_in[2];
  const float* fb = (const float*)d_in[3];
  const float* bW = (const float*)d_in[4];
  const float* bU = (const float*)d_in[5];
  const float* bb = (const float*)d_in[6];
  u16*   xwbuf = (u16*)d_ws;
  u16*   UT    = (u16*)d_ws + XW_ELEMS;
  float* out   = (float*)d_out;

  const bool fast = ws_size >= (XW_ELEMS + UT_ELEMS) * sizeof(u16);

  dim3 g1(16, 16);
  xw_gemm<<<g1, 256, 0, stream>>>(x, fW, bW, fb, bb, xwbuf);
  if (fast) {
    build_ut<<<8, 1024, 0, stream>>>(fU, bU, UT);
    hipFuncSetAttribute((const void*)lstm_scan_fast,
                        hipFuncAttributeMaxDynamicSharedMemorySize, 147456);
    lstm_scan_fast<<<8, 1024, 147456, stream>>>(xwbuf, UT, out);
  } else {
    lstm_scan_safe<<<8, 1024, 0, stream>>>(xwbuf, fU, bU, out);
  }
}

// Round 4
// 3920.418 us; speedup vs baseline: 2.6044x; 1.2772x over previous
//
#include <hip/hip_runtime.h>

#define T_STEPS 1024
#define BATCH   64
#define NDIM    256
#define HID     256
#define G4      1024   // 4*H

typedef short bf16x8 __attribute__((ext_vector_type(8)));
typedef float f32x4  __attribute__((ext_vector_type(4)));
typedef unsigned short u16;

#define XW_ELEMS ((size_t)2 * T_STEPS * BATCH * G4)   // 134217728 u16 (256 MiB)
#define UT_ELEMS ((size_t)2 * 4 * 65536)              // 524288 u16 (1 MiB)

__device__ __forceinline__ float b2f(u16 v) {
  union { unsigned u; float f; } c; c.u = ((unsigned)v) << 16; return c.f;
}
__device__ __forceinline__ u16 f2b(float f) {
  union { float f; unsigned u; } c; c.f = f;
  unsigned u = c.u;
  u += 0x7fffu + ((u >> 16) & 1u);   // round-to-nearest-even
  return (u16)(u >> 16);
}
__device__ __forceinline__ float sigm(float x) {
  float e = __expf(-x);
  return __builtin_amdgcn_rcpf(1.0f + e);
}
__device__ __forceinline__ float tanh_f(float x) {
  return 2.0f * sigm(2.0f * x) - 1.0f;
}

// ---------------------------------------------------------------------------
// build_ut: pre-transpose U (f32) into bf16 MFMA B-fragment order.
// UT elem idx: ((d*4+g)*65536) + ((w*8+kf)*64 + lane)*8 + j
// ---------------------------------------------------------------------------
__global__ __launch_bounds__(1024) void build_ut(
    const float* __restrict__ U0, const float* __restrict__ U1,
    u16* __restrict__ UT)
{
  const int d = blockIdx.x >> 2;
  const int g = blockIdx.x & 3;
  const float* __restrict__ U = d ? U1 : U0;
  const int w = threadIdx.x >> 6, lane = threadIdx.x & 63;
  const int q = lane >> 4, c15 = lane & 15;
  u16* dst = UT + ((size_t)d * 4 + g) * 65536;
  #pragma unroll
  for (int kf = 0; kf < 8; ++kf) {
    bf16x8 v;
    #pragma unroll
    for (int j = 0; j < 8; ++j)
      v[j] = (short)f2b(U[(size_t)(kf * 32 + q * 8 + j) * G4 + g * 256 + w * 16 + c15]);
    ((bf16x8*)dst)[((w * 8 + kf) << 6) + lane] = v;
  }
}

// ---------------------------------------------------------------------------
// Phase 1: xw = x @ W_d + b_d, bf16, scan-consumption order:
//   elem idx = (((d*T + t)*4 + bt)*1024 + tid)*16 + gate*4 + r
// 64-col N-tiles (uf = 128 VGPRs), t-chunk 32 -> grid 1024 blocks, 2 blk/CU.
// ---------------------------------------------------------------------------
__global__ __launch_bounds__(256, 2) void xw_gemm(
    const float* __restrict__ x,
    const float* __restrict__ W0, const float* __restrict__ W1,
    const float* __restrict__ b0, const float* __restrict__ b1,
    u16* __restrict__ xw)
{
  const int d  = blockIdx.y >> 4;
  const int n0 = (blockIdx.y & 15) * 64;
  const int t0 = blockIdx.x * 32;
  const float* __restrict__ W    = d ? W1 : W0;
  const float* __restrict__ bias = d ? b1 : b0;
  const int lane = threadIdx.x & 63;
  const int wv   = threadIdx.x >> 6;
  const int q    = lane >> 4;
  const int c15  = lane & 15;

  bf16x8 uf[4][8];
  #pragma unroll
  for (int ct = 0; ct < 4; ++ct) {
    const int col = n0 + ct * 16 + c15;
    #pragma unroll
    for (int kf = 0; kf < 8; ++kf) {
      #pragma unroll
      for (int j = 0; j < 8; ++j)
        uf[ct][kf][j] = (short)f2b(W[(size_t)(kf * 32 + q * 8 + j) * G4 + col]);
    }
  }
  float bc[4];
  #pragma unroll
  for (int ct = 0; ct < 4; ++ct) bc[ct] = bias[n0 + ct * 16 + c15];

  __shared__ __align__(16) u16 Alds[64 * 256];

  for (int t = t0; t < t0 + 32; ++t) {
    __syncthreads();
    const float* xt = x + (size_t)t * BATCH * NDIM;
    #pragma unroll
    for (int i = 0; i < 8; ++i) {
      int g = (int)threadIdx.x + 256 * i;
      int r = g >> 5, c = g & 31;
      const float* src = xt + r * 256 + c * 8;
      bf16x8 v;
      #pragma unroll
      for (int j = 0; j < 8; ++j) v[j] = (short)f2b(src[j]);
      int cs = (c & 16) | ((c ^ (r & 15)) & 15);
      ((bf16x8*)Alds)[r * 32 + cs] = v;
    }
    __syncthreads();

    bf16x8 af[8];
    const int arow = wv * 16 + c15;
    #pragma unroll
    for (int kf = 0; kf < 8; ++kf) {
      int c = kf * 4 + q;
      int cs = (c & 16) | ((c ^ c15) & 15);
      af[kf] = ((const bf16x8*)Alds)[arow * 32 + cs];
    }

    f32x4 acc[4];
    #pragma unroll
    for (int ct = 0; ct < 4; ++ct) acc[ct] = (f32x4){0.f, 0.f, 0.f, 0.f};
    #pragma unroll
    for (int kf = 0; kf < 8; ++kf) {
      #pragma unroll
      for (int ct = 0; ct < 4; ++ct)
        acc[ct] = __builtin_amdgcn_mfma_f32_16x16x32_bf16(af[kf], uf[ct][kf], acc[ct], 0, 0, 0);
    }

    u16* dst = xw + (((size_t)d * T_STEPS + t) * 4 + wv) * 16384;
    #pragma unroll
    for (int ct = 0; ct < 4; ++ct) {
      int ncol = n0 + ct * 16;
      int g2 = ncol >> 8, w2 = (ncol >> 4) & 15;
      union { u16 s[4]; uint2 v; } pk;
      #pragma unroll
      for (int r = 0; r < 4; ++r) pk.s[r] = f2b(acc[ct][r] + bc[ct]);
      *(uint2*)(dst + (size_t)(w2 * 64 + q * 16 + c15) * 16 + g2 * 4) = pk.v;
    }
  }
}

// ---------------------------------------------------------------------------
// Phase 2 (fast): grid 8 = (d, bt). 16 waves; wave w owns h-cols [w*16,+16).
// U by gate: f,g in 64 VGPRs; i in 128 KB LDS; o streamed from L2 (rolling
// buffer crossing the step boundary). acc seeded with xw pre-activations
// (prefetched one step ahead). Walking pointers for out/xw.
// Dynamic LDS 147456 B: [0,16384) h ping-pong (8 KB each), [16384,..) U_i.
// ---------------------------------------------------------------------------
__global__ __launch_bounds__(1024) void lstm_scan_fast(
    const u16* __restrict__ xw, const u16* __restrict__ UT,
    float* __restrict__ out)
{
  extern __shared__ __align__(16) u16 dynlds[];
  const int d  = blockIdx.x >> 2;
  const int bt = blockIdx.x & 3;
  const int tid  = threadIdx.x;
  const int w    = tid >> 6;
  const int lane = tid & 63;
  const int q    = lane >> 4;
  const int c15  = lane & 15;

  const u16* __restrict__ UTd = UT + (size_t)d * 4 * 65536;

  // persistent register fragments for gates f(0), g(1)
  bf16x8 uf0[8], uf1[8];
  const bf16x8* UTf = (const bf16x8*)UTd;
  #pragma unroll
  for (int kf = 0; kf < 8; ++kf) {
    uf0[kf] = UTf[       ((w * 8 + kf) << 6) + lane];
    uf1[kf] = UTf[8192 + ((w * 8 + kf) << 6) + lane];
  }

  // stage i-gate into LDS + zero both h buffers
  {
    const int4* src = (const int4*)(UTd + 2 * 65536);
    int4* dstl = (int4*)(dynlds + 8192);
    for (int i = tid; i < 8192; i += 1024) dstl[i] = src[i];
    for (int i = tid; i < 8192; i += 1024) dynlds[i] = 0;
  }

  const int4* __restrict__ Uo4 = (const int4*)(UTd + 3 * 65536);
  const int obase = (w << 9) | lane;
  const char* uib_base = (const char*)(dynlds + 8192) + (size_t)obase * 16;  // +kf*1024 imm

  // precomputed LDS byte offsets; h buffer selected by XOR 8192
  int afo[8];
  #pragma unroll
  for (int kf = 0; kf < 8; ++kf) {
    int cc = kf * 4 + q;
    int cs = (cc & 16) | ((cc ^ c15) & 15);
    afo[kf] = (c15 * 32 + cs) * 16;
  }
  const int colv = w * 16 + c15;
  int hwo[4];
  #pragma unroll
  for (int r = 0; r < 4; ++r) {
    int row = q * 4 + r;
    int cch = colv >> 3;
    int cs = (cch & 16) | ((cch ^ row) & 15);
    hwo[r] = ((row * 32 + cs) * 8 + (colv & 7)) * 2;
  }

  float cst[4] = {0.f, 0.f, 0.f, 0.f};
  __syncthreads();

  const int rowbase = bt * 16;
  const size_t hlast_base = (size_t)T_STEPS * BATCH * (2 * HID) + (size_t)d * BATCH * HID;
  const int t_first = d ? (T_STEPS - 1) : 0;

  // xw walking pointer; prefetch step 0
  const long xw_stride = d ? -(long)(4 * 16384) : (long)(4 * 16384);
  const u16* xwp = xw + (((size_t)d * T_STEPS + t_first) * 4 + bt) * 16384 + (size_t)tid * 16;
  union I4x2 { int4 v[2]; u16 s[16]; };
  I4x2 xn;
  xn.v[0] = ((const int4*)xwp)[0];
  xn.v[1] = ((const int4*)xwp)[1];
  xwp += xw_stride;

  // o-gate rolling L2 stream (persistent across the step boundary)
  int4 ofr[3];
  ofr[0] = Uo4[obase];
  ofr[1] = Uo4[obase + 64];

  // out walking pointer
  float* outp = out + (size_t)(t_first * BATCH + rowbase + q * 4) * (2 * HID)
              + (size_t)d * HID + colv;
  const long out_stride = d ? -(long)(BATCH * 2 * HID) : (long)(BATCH * 2 * HID);

  int curoff = 0;
  for (int it = 0; it < T_STEPS; ++it) {
    // seed accumulators with current step's pre-activations
    f32x4 acc0 = { b2f(xn.s[0]),  b2f(xn.s[1]),  b2f(xn.s[2]),  b2f(xn.s[3])  };
    f32x4 acc1 = { b2f(xn.s[4]),  b2f(xn.s[5]),  b2f(xn.s[6]),  b2f(xn.s[7])  };
    f32x4 acc2 = { b2f(xn.s[8]),  b2f(xn.s[9]),  b2f(xn.s[10]), b2f(xn.s[11]) };
    f32x4 acc3 = { b2f(xn.s[12]), b2f(xn.s[13]), b2f(xn.s[14]), b2f(xn.s[15]) };

    // prefetch next step's xw (hidden under this step's MFMA+gates)
    if (it + 1 < T_STEPS) {
      xn.v[0] = ((const int4*)xwp)[0];
      xn.v[1] = ((const int4*)xwp)[1];
      xwp += xw_stride;
    }

    const char* hcb = (const char*)dynlds + curoff;
    bf16x8 afb[2], uib[2];
    afb[0] = *(const bf16x8*)(hcb + afo[0]);
    uib[0] = *(const bf16x8*)(uib_base);
    #pragma unroll
    for (int kf = 0; kf < 8; ++kf) {
      if (kf < 7) {
        afb[(kf + 1) & 1] = *(const bf16x8*)(hcb + afo[kf + 1]);
        uib[(kf + 1) & 1] = *(const bf16x8*)(uib_base + (kf + 1) * 1024);
      }
      if (kf < 6) ofr[(kf + 2) % 3] = Uo4[obase + ((kf + 2) << 6)];
      bf16x8 af = afb[kf & 1];
      union { int4 v; bf16x8 b; } oc; oc.v = ofr[kf % 3];
      acc0 = __builtin_amdgcn_mfma_f32_16x16x32_bf16(af, uf0[kf],     acc0, 0, 0, 0);
      acc1 = __builtin_amdgcn_mfma_f32_16x16x32_bf16(af, uf1[kf],     acc1, 0, 0, 0);
      acc2 = __builtin_amdgcn_mfma_f32_16x16x32_bf16(af, uib[kf & 1], acc2, 0, 0, 0);
      acc3 = __builtin_amdgcn_mfma_f32_16x16x32_bf16(af, oc.b,        acc3, 0, 0, 0);
    }
    // refill o-stream head for NEXT step now; latency hides under the gates
    ofr[0] = Uo4[obase];
    ofr[1] = Uo4[obase + 64];

    u16 hb[4]; float hv[4];
    #pragma unroll
    for (int r = 0; r < 4; ++r) {
      float fg = sigm(acc0[r]);
      float gg = tanh_f(acc1[r]);
      float ig = sigm(acc2[r]);
      float og = sigm(acc3[r]);
      float cn = cst[r] * fg + gg * ig;
      cst[r] = cn;
      hv[r] = og * tanh_f(cn);
      hb[r] = f2b(hv[r]);
    }

    const int nxtoff = curoff ^ 8192;
    char* hwp = (char*)dynlds + nxtoff;
    #pragma unroll
    for (int r = 0; r < 4; ++r) {
      *(u16*)(hwp + hwo[r]) = hb[r];
      outp[r * (2 * HID)] = hv[r];          // imm offsets 0/2048/4096/6144 B
    }
    outp += out_stride;
    if (it == T_STEPS - 1) {
      #pragma unroll
      for (int r = 0; r < 4; ++r)
        out[hlast_base + (size_t)(rowbase + q * 4 + r) * HID + colv] = hv[r];
    }
    curoff = nxtoff;
    __syncthreads();
  }
}

// ---------------------------------------------------------------------------
// Phase 2 (safe fallback if ws too small for UT): correct but slow.
// ---------------------------------------------------------------------------
__global__ __launch_bounds__(1024) void lstm_scan_safe(
    const u16* __restrict__ xw,
    const float* __restrict__ U0, const float* __restrict__ U1,
    float* __restrict__ out)
{
  const int d  = blockIdx.x >> 2;
  const int bt = blockIdx.x & 3;
  const int tid  = threadIdx.x;
  const int w    = tid >> 6;
  const int lane = tid & 63;
  const int q    = lane >> 4;
  const int c15  = lane & 15;
  const float* __restrict__ U = d ? U1 : U0;

  bf16x8 uf[4][8];
  #pragma unroll
  for (int g = 0; g < 4; ++g) {
    const int col2 = g * 256 + w * 16 + c15;
    #pragma unroll
    for (int kf = 0; kf < 8; ++kf) {
      #pragma unroll
      for (int j = 0; j < 8; ++j)
        uf[g][kf][j] = (short)f2b(U[(size_t)(kf * 32 + q * 8 + j) * G4 + col2]);
    }
  }

  __shared__ __align__(16) u16 hbuf[2][16 * 256];
  for (int i = tid; i < 16 * 256; i += 1024) { hbuf[0][i] = 0; hbuf[1][i] = 0; }
  float cst[4] = {0.f, 0.f, 0.f, 0.f};
  __syncthreads();

  const int rowbase = bt * 16;
  const int col = w * 16 + c15;
  const size_t hlast_base = (size_t)T_STEPS * BATCH * (2 * HID) + (size_t)d * BATCH * HID;

  for (int it = 0; it < T_STEPS; ++it) {
    const int t = d ? (T_STEPS - 1 - it) : it;
    union { int4 v[2]; u16 s[16]; } xv;
    {
      const int4* xwt = (const int4*)(xw + ((((size_t)d * T_STEPS + t) * 4 + bt) * 1024 + tid) * 16);
      xv.v[0] = xwt[0]; xv.v[1] = xwt[1];
    }
    const int cur = it & 1;
    bf16x8 af[8];
    #pragma unroll
    for (int kf = 0; kf < 8; ++kf) {
      int cc = kf * 4 + q;
      int cs = (cc & 16) | ((cc ^ c15) & 15);
      af[kf] = ((const bf16x8*)hbuf[cur])[c15 * 32 + cs];
    }
    f32x4 acc[4];
    #pragma unroll
    for (int g = 0; g < 4; ++g) acc[g] = (f32x4){0.f, 0.f, 0.f, 0.f};
    #pragma unroll
    for (int kf = 0; kf < 8; ++kf)
      #pragma unroll
      for (int g = 0; g < 4; ++g)
        acc[g] = __builtin_amdgcn_mfma_f32_16x16x32_bf16(af[kf], uf[g][kf], acc[g], 0, 0, 0);

    u16 hb[4]; float hv[4];
    #pragma unroll
    for (int r = 0; r < 4; ++r) {
      float zf = acc[0][r] + b2f(xv.s[0 * 4 + r]);
      float zg = acc[1][r] + b2f(xv.s[1 * 4 + r]);
      float zi = acc[2][r] + b2f(xv.s[2 * 4 + r]);
      float zo = acc[3][r] + b2f(xv.s[3 * 4 + r]);
      float fg = sigm(zf), gg = tanh_f(zg), ig = sigm(zi), og = sigm(zo);
      float cn = cst[r] * fg + gg * ig;
      cst[r] = cn;
      hv[r] = og * tanh_f(cn);
      hb[r] = f2b(hv[r]);
    }
    const int nxt = cur ^ 1;
    #pragma unroll
    for (int r = 0; r < 4; ++r) {
      const int row = q * 4 + r;
      int cch = col >> 3;
      int cs = (cch & 16) | ((cch ^ row) & 15);
      hbuf[nxt][(row * 32 + cs) * 8 + (col & 7)] = hb[r];
      out[((size_t)t * BATCH + rowbase + row) * (2 * HID) + (size_t)d * HID + col] = hv[r];
    }
    if (it == T_STEPS - 1) {
      #pragma unroll
      for (int r = 0; r < 4; ++r)
        out[hlast_base + (size_t)(rowbase + q * 4 + r) * HID + col] = hv[r];
    }
    __syncthreads();
  }
}

extern "C" void kernel_launch(void* const* d_in, const int* in_sizes, int n_in,
                              void* d_out, int out_size, void* d_ws, size_t ws_size,
                              hipStream_t stream) {
  const float* x  = (const float*)d_in[0];
  const float* fW = (const float*)d_in[1];
  const float* fU = (const float*)d_in[2];
  const float* fb = (const float*)d_in[3];
  const float* bW = (const float*)d_in[4];
  const float* bU = (const float*)d_in[5];
  const float* bb = (const float*)d_in[6];
  u16*   xwbuf = (u16*)d_ws;
  u16*   UT    = (u16*)d_ws + XW_ELEMS;
  float* out   = (float*)d_out;

  const bool fast = ws_size >= (XW_ELEMS + UT_ELEMS) * sizeof(u16);

  dim3 g1(32, 32);
  xw_gemm<<<g1, 256, 0, stream>>>(x, fW, bW, fb, bb, xwbuf);
  if (fast) {
    build_ut<<<8, 1024, 0, stream>>>(fU, bU, UT);
    hipFuncSetAttribute((const void*)lstm_scan_fast,
                        hipFuncAttributeMaxDynamicSharedMemorySize, 147456);
    lstm_scan_fast<<<8, 1024, 147456, stream>>>(xwbuf, UT, out);
  } else {
    lstm_scan_safe<<<8, 1024, 0, stream>>>(xwbuf, fU, bU, out);
  }
}